// Round 16
// baseline (104.538 us; speedup 1.0000x reference)
//
#include <hip/hip_runtime.h>
#include <math.h>

#define N_NODES 1024
#define DEG     24
#define K_NN    12
#define C_S     384
#define C_Z     128
#define C_G     16
#define N_RBF   64
#define N_EDGES (N_NODES*DEG)

typedef short short8 __attribute__((ext_vector_type(8)));
typedef float f32x4  __attribute__((ext_vector_type(4)));

__device__ __forceinline__ float sigf(float x) {
  return __builtin_amdgcn_rcpf(1.f + __expf(-x));
}

// float -> bf16 (RNE)
__device__ __forceinline__ short f2b(float x) {
  union { float f; unsigned u; } v; v.f = x;
  unsigned r = v.u + 0x7FFFu + ((v.u >> 16) & 1u);
  return (short)(r >> 16);
}
__device__ __forceinline__ float b2f(short s) {
  union { unsigned u; float f; } v; v.u = ((unsigned)(unsigned short)s) << 16;
  return v.f;
}

// ---------------- K1: all input-only prep (R12 form, unchanged) ----------------
__global__ __launch_bounds__(256) void k_prep(
    const float* __restrict__ nf, const float* __restrict__ wl_w, const float* __restrict__ wl_b,
    const float* __restrict__ wr_w, const float* __restrict__ wr_b,
    const float* __restrict__ dg_w,
    const float* __restrict__ eg, const float* __restrict__ ep,
    const float* __restrict__ og, const float* __restrict__ lo,
    const float* __restrict__ dp_w,
    short* __restrict__ nlB, short* __restrict__ At,
    short* __restrict__ wT, short* __restrict__ dpT)
{
  __shared__ float rows[4][C_S];
  __shared__ float nrv[4][C_G];
  __shared__ float tb[32][33];
  int b = blockIdx.x, t = threadIdx.x;
  if (b < 256) {
    for (int v = t; v < 4*C_S; v += 256) rows[v/C_S][v%C_S] = nf[(size_t)b*4*C_S + v];
    __syncthreads();
    {
      int nd = t >> 6, lt = t & 63;
      int c = lt >> 1, jseg = lt & 1, cc = c & 15;
      const float* w = (c < 16) ? wl_w : wr_w;
      float acc = 0.f;
      #pragma unroll 8
      for (int j = jseg*192; j < jseg*192 + 192; ++j) acc += rows[nd][j] * w[j*C_G + cc];
      acc += __shfl_xor(acc, 1);
      if (jseg == 0) {
        float v = acc + ((c < 16) ? wl_b[cc] : wr_b[cc]);
        if (c < 16) nlB[(b*4 + nd)*C_G + cc] = f2b(v);
        else nrv[nd][cc] = v;
      }
    }
    __syncthreads();
    {
      int c2 = t & 127, ih = t >> 7;
      float a4[4][8];
      #pragma unroll
      for (int nd = 0; nd < 4; ++nd)
        #pragma unroll
        for (int q = 0; q < 8; ++q) a4[nd][q] = 0.f;
      for (int j = 0; j < C_G; ++j) {
        float w8[8];
        #pragma unroll
        for (int q = 0; q < 8; ++q) w8[q] = dg_w[(size_t)((ih*8 + q)*C_G + j)*C_Z + c2];
        #pragma unroll
        for (int nd = 0; nd < 4; ++nd) {
          float nv = nrv[nd][j];
          #pragma unroll
          for (int q = 0; q < 8; ++q) a4[nd][q] += nv * w8[q];
        }
      }
      #pragma unroll
      for (int nd = 0; nd < 4; ++nd) {
        short8 o8;
        #pragma unroll
        for (int q = 0; q < 8; ++q) o8[q] = f2b(a4[nd][q]);
        *(short8*)&At[(size_t)(b*4 + nd)*2048 + c2*16 + ih*8] = o8;
      }
    }
    return;
  }
  if (b < 320) {
    int bb = b - 256;
    int w = bb >> 4, tile = bb & 15, bi = tile >> 2, bj = tile & 3;
    const float* src = (w == 0) ? eg : (w == 1) ? ep : (w == 2) ? og : lo;
    short* dst = wT + w * 16384;
    int c = t & 31, r0 = t >> 5;
    #pragma unroll
    for (int p = 0; p < 4; ++p) { int r = r0 + p*8; tb[r][c] = src[(bi*32 + r)*128 + bj*32 + c]; }
    __syncthreads();
    #pragma unroll
    for (int p = 0; p < 4; ++p) { int r = r0 + p*8; dst[(bj*32 + r)*128 + bi*32 + c] = f2b(tb[c][r]); }
    return;
  }
  {
    int c2 = t & 127, rh = t >> 7;
    for (int r = rh*36; r < rh*36 + 36; ++r)
      dpT[c2*72 + r] = (r < 64) ? f2b(dp_w[r*128 + c2]) : (short)0;
  }
}

// ---------------- K2: gates ∥ pairs in ONE launch (independent dataflow) ----------------
// blocks 0..6143: pairs, one edge per wave (R9 exact core), writes RAW S (f32) — no e2,
//   no LN, no f2b tail. blocks 6144..7679: LN + 3 gate GEMVs per 16-edge tile.
// Both depend only on k_prep outputs; co-scheduling hides gates' ~13us under pairs.
__global__ __launch_bounds__(256) void k_gp(
    const int* __restrict__ eidx, const float* __restrict__ pos,
    const short* __restrict__ nlB, const short* __restrict__ At, const short* __restrict__ dpTg,
    const float* __restrict__ dg_b, const float* __restrict__ dp_b,
    float* __restrict__ S,
    const float* __restrict__ efin, const float* __restrict__ ln_w, const float* __restrict__ ln_b,
    const short* __restrict__ wT,
    const float* __restrict__ eg_b, const float* __restrict__ ep_b, const float* __restrict__ og_b,
    float* __restrict__ e2, short* __restrict__ ogs)
{
  __shared__ float p4[DEG][4];
  __shared__ int   s24[DEG];
  __shared__ short nlb[DEG*C_G];
  __shared__ short xn[16*136];
  int b = blockIdx.x, t = threadIdx.x;
  int wv = t >> 6, lane = t & 63, col = lane & 15, grp = lane >> 4;

  if (b < 6144) {
    // ---- pairs path ----
    int g = b / 6, sub = b - g*6;
    if (t < DEG) {
      int s = eidx[g*DEG + t];
      s24[t] = s;
      p4[t][0] = pos[s*3+0]; p4[t][1] = pos[s*3+1]; p4[t][2] = pos[s*3+2]; p4[t][3] = 0.f;
    }
    __syncthreads();
    for (int v = t; v < DEG*C_G; v += 256)
      nlb[v] = nlB[s24[v>>4]*C_G + (v & 15)];
    __syncthreads();

    int o = sub*4 + wv;
    size_t e = (size_t)g*DEG + o;

    float dgb[8], dpb[8];
    #pragma unroll
    for (int q = 0; q < 8; ++q) { int c = col+16*q; dgb[q] = dg_b[c]; dpb[q] = dp_b[c]; }
    const float RS = 3.2f, MUS = 20.f/63.f;

    int n2 = s24[o];
    int o2 = o - 1 - col; if (o2 < 0) o2 += DEG;
    bool vk = (col < K_NN);
    float d;
    {
      float dx = p4[o2][0]-p4[o][0]+1e-8f;
      float dy = p4[o2][1]-p4[o][1]+1e-8f;
      float dz = p4[o2][2]-p4[o][2]+1e-8f;
      d = vk ? sqrtf(dx*dx+dy*dy+dz*dz) : 1.0e6f;
    }
    short8 zz = {0,0,0,0,0,0,0,0};
    short8 a_nl = zz;
    if (vk && grp < 2) a_nl = *(const short8*)&nlb[o2*C_G + grp*8];
    short8 a_r0, a_r1;
    #pragma unroll
    for (int j = 0; j < 8; ++j) {
      float z0 = (d - (float)(grp*8 + j)*MUS)*RS;
      float z1 = (d - (float)(32 + grp*8 + j)*MUS)*RS;
      a_r0[j] = f2b(__expf(-z0*z0));
      a_r1[j] = f2b(__expf(-z1*z1));
    }
    const short8* Ab = (const short8*)(At + (size_t)n2*2048);
    float v1 = 0.f, v2 = 0.f;
    #pragma unroll
    for (int cb = 0; cb < 8; ++cb) {
      f32x4 accg = (f32x4){0.f,0.f,0.f,0.f};
      f32x4 accd = (f32x4){0.f,0.f,0.f,0.f};
      short8 bb = (grp < 2) ? Ab[(col+16*cb)*2 + grp] : zz;
      accg = __builtin_amdgcn_mfma_f32_16x16x32_bf16(a_nl, bb, accg, 0, 0, 0);
      const short* dbase = dpTg + (col+16*cb)*72 + grp*8;
      accd = __builtin_amdgcn_mfma_f32_16x16x32_bf16(a_r0, *(const short8*)dbase,      accd, 0, 0, 0);
      accd = __builtin_amdgcn_mfma_f32_16x16x32_bf16(a_r1, *(const short8*)(dbase+32), accd, 0, 0, 0);
      float sacc = 0.f;
      #pragma unroll
      for (int r = 0; r < 4; ++r)
        sacc += sigf(accg[r] + dgb[cb]) * (accd[r] + dpb[cb]);
      sacc = (grp == 3) ? 0.f : sacc;   // mask k rows 12..15
      sacc += __shfl_xor(sacc, 16); sacc += __shfl_xor(sacc, 32);
      v1 = (cb == grp)     ? sacc : v1;
      v2 = (cb == grp + 4) ? sacc : v2;
    }
    S[e*C_Z + lane]      = v1;
    S[e*C_Z + 64 + lane] = v2;
    return;
  }

  // ---- gates path ----
  {
    int ebase = (b - 6144) * 16;
    {
      int el = t >> 4, sub = t & 15, c0 = sub*8;
      float x[8];
      size_t ein = (size_t)(ebase + el) * C_Z + c0;
      float4 v0 = *(const float4*)(efin + ein);
      float4 v1 = *(const float4*)(efin + ein + 4);
      x[0]=v0.x; x[1]=v0.y; x[2]=v0.z; x[3]=v0.w;
      x[4]=v1.x; x[5]=v1.y; x[6]=v1.z; x[7]=v1.w;
      float s = 0.f;
      #pragma unroll
      for (int q = 0; q < 8; ++q) s += x[q];
      s += __shfl_xor(s,1); s += __shfl_xor(s,2); s += __shfl_xor(s,4); s += __shfl_xor(s,8);
      float mean = s * (1.f/128.f);
      float vs = 0.f;
      #pragma unroll
      for (int q = 0; q < 8; ++q) { float dd = x[q]-mean; vs += dd*dd; }
      vs += __shfl_xor(vs,1); vs += __shfl_xor(vs,2); vs += __shfl_xor(vs,4); vs += __shfl_xor(vs,8);
      float rstd = rsqrtf(vs*(1.f/128.f) + 1e-5f);
      short8 o;
      #pragma unroll
      for (int q = 0; q < 8; ++q)
        o[q] = f2b((x[q]-mean)*rstd*ln_w[c0+q] + ln_b[c0+q]);
      *(short8*)&xn[el*136 + c0] = o;
    }
    __syncthreads();
    short8 a[4];
    #pragma unroll
    for (int ks = 0; ks < 4; ++ks)
      a[ks] = *(const short8*)&xn[col*136 + ks*32 + grp*8];
    #pragma unroll
    for (int hh = 0; hh < 2; ++hh) {
      int ch = col + 16*(wv*2 + hh);
      f32x4 aE = (f32x4){0.f,0.f,0.f,0.f}, aP = aE, aO = aE;
      #pragma unroll
      for (int ks = 0; ks < 4; ++ks) {
        aE = __builtin_amdgcn_mfma_f32_16x16x32_bf16(
            a[ks], *(const short8*)(wT + (size_t)ch*128 + ks*32 + grp*8), aE, 0, 0, 0);
        aP = __builtin_amdgcn_mfma_f32_16x16x32_bf16(
            a[ks], *(const short8*)(wT + 16384 + (size_t)ch*128 + ks*32 + grp*8), aP, 0, 0, 0);
        aO = __builtin_amdgcn_mfma_f32_16x16x32_bf16(
            a[ks], *(const short8*)(wT + 32768 + (size_t)ch*128 + ks*32 + grp*8), aO, 0, 0, 0);
      }
      float egb = eg_b[ch], epb = ep_b[ch], ogb = og_b[ch];
      #pragma unroll
      for (int r = 0; r < 4; ++r) {
        size_t e = (size_t)(ebase + grp*4 + r);
        e2[e*C_Z + ch]  = sigf(aE[r] + egb) * (aP[r] + epb);
        ogs[e*C_Z + ch] = f2b(sigf(aO[r] + ogb));
      }
    }
  }
}

// ---------------- K3: out = (LN(S*e2) @ lo_w + lo_b) * ogs — in-register LN, barrier-free ----------------
// Wave = 16-edge tile; lane (col,grp) holds all 32 channels {ks*32+grp*8+j} of edge col
// = exactly the A-fragment layout, so U-LN is 2 shuffles in registers (no LDS).
__global__ __launch_bounds__(256) void k_out4(
    const float* __restrict__ S, const float* __restrict__ e2,
    const float* __restrict__ lno_w, const float* __restrict__ lno_b,
    const short* __restrict__ wTlo, const float* __restrict__ lo_b,
    const short* __restrict__ ogs, float* __restrict__ out)
{
  int t = threadIdx.x, wv = t >> 6, lane = t & 63, col = lane & 15, grp = lane >> 4;
  int ebase = blockIdx.x * 16;
  size_t e = (size_t)(ebase + col);

  float u[32];
  float s = 0.f;
  #pragma unroll
  for (int ks = 0; ks < 4; ++ks) {
    size_t base = e*C_Z + ks*32 + grp*8;
    float4 s0 = *(const float4*)(S + base);
    float4 s1 = *(const float4*)(S + base + 4);
    float4 g0 = *(const float4*)(e2 + base);
    float4 g1 = *(const float4*)(e2 + base + 4);
    u[ks*8+0] = s0.x*g0.x; u[ks*8+1] = s0.y*g0.y; u[ks*8+2] = s0.z*g0.z; u[ks*8+3] = s0.w*g0.w;
    u[ks*8+4] = s1.x*g1.x; u[ks*8+5] = s1.y*g1.y; u[ks*8+6] = s1.z*g1.z; u[ks*8+7] = s1.w*g1.w;
    #pragma unroll
    for (int j = 0; j < 8; ++j) s += u[ks*8+j];
  }
  s += __shfl_xor(s, 16); s += __shfl_xor(s, 32);
  float mean = s * (1.f/128.f);
  float vs = 0.f;
  #pragma unroll
  for (int q = 0; q < 32; ++q) { float dd = u[q]-mean; vs += dd*dd; }
  vs += __shfl_xor(vs, 16); vs += __shfl_xor(vs, 32);
  float rstd = rsqrtf(vs*(1.f/128.f) + 1e-5f);

  short8 ua[4];
  #pragma unroll
  for (int ks = 0; ks < 4; ++ks) {
    int cb = ks*32 + grp*8;
    float4 w0 = *(const float4*)(lno_w + cb);
    float4 w1 = *(const float4*)(lno_w + cb + 4);
    float4 b0 = *(const float4*)(lno_b + cb);
    float4 b1 = *(const float4*)(lno_b + cb + 4);
    ua[ks][0] = f2b((u[ks*8+0]-mean)*rstd*w0.x + b0.x);
    ua[ks][1] = f2b((u[ks*8+1]-mean)*rstd*w0.y + b0.y);
    ua[ks][2] = f2b((u[ks*8+2]-mean)*rstd*w0.z + b0.z);
    ua[ks][3] = f2b((u[ks*8+3]-mean)*rstd*w0.w + b0.w);
    ua[ks][4] = f2b((u[ks*8+4]-mean)*rstd*w1.x + b1.x);
    ua[ks][5] = f2b((u[ks*8+5]-mean)*rstd*w1.y + b1.y);
    ua[ks][6] = f2b((u[ks*8+6]-mean)*rstd*w1.z + b1.z);
    ua[ks][7] = f2b((u[ks*8+7]-mean)*rstd*w1.w + b1.w);
  }

  #pragma unroll
  for (int hh = 0; hh < 2; ++hh) {
    int ch = col + 16*(wv*2 + hh);
    f32x4 oacc = (f32x4){0.f,0.f,0.f,0.f};
    #pragma unroll
    for (int ks = 0; ks < 4; ++ks)
      oacc = __builtin_amdgcn_mfma_f32_16x16x32_bf16(
          ua[ks], *(const short8*)(wTlo + (size_t)ch*128 + ks*32 + grp*8), oacc, 0, 0, 0);
    float lob = lo_b[ch];
    #pragma unroll
    for (int r = 0; r < 4; ++r) {
      size_t eo = (size_t)(ebase + grp*4 + r);
      out[eo*C_Z + ch] = (oacc[r] + lob) * b2f(ogs[eo*C_Z + ch]);
    }
  }
}

extern "C" void kernel_launch(void* const* d_in, const int* in_sizes, int n_in,
                              void* d_out, int out_size, void* d_ws, size_t ws_size,
                              hipStream_t stream)
{
  const float* nf    = (const float*)d_in[0];
  const float* pos   = (const float*)d_in[1];
  const float* efin  = (const float*)d_in[2];
  const float* ln_w  = (const float*)d_in[3];
  const float* ln_b  = (const float*)d_in[4];
  const float* wl_w  = (const float*)d_in[5];
  const float* wl_b  = (const float*)d_in[6];
  const float* wr_w  = (const float*)d_in[7];
  const float* wr_b  = (const float*)d_in[8];
  const float* ep_w  = (const float*)d_in[9];
  const float* ep_b  = (const float*)d_in[10];
  const float* eg_w  = (const float*)d_in[11];
  const float* eg_b  = (const float*)d_in[12];
  const float* dg_w  = (const float*)d_in[13];
  const float* dg_b  = (const float*)d_in[14];
  const float* dp_w  = (const float*)d_in[15];
  const float* dp_b  = (const float*)d_in[16];
  const float* lno_w = (const float*)d_in[17];
  const float* lno_b = (const float*)d_in[18];
  const float* lo_w  = (const float*)d_in[19];
  const float* lo_b  = (const float*)d_in[20];
  const float* og_w  = (const float*)d_in[21];
  const float* og_b  = (const float*)d_in[22];
  const int*   eidx  = (const int*)d_in[23];
  // d_in[24] = edge_edge_index: structure derived analytically, not read.

  float* ws   = (float*)d_ws;
  short* nlBw = (short*)(ws + 0);        //  16384 bf16
  short* dpTw = (short*)(ws + 8192);     //   9216 bf16
  short* wTw  = (short*)(ws + 16384);    //  65536 bf16 (eg,ep,og,lo)
  short* Atw  = (short*)(ws + 49152);    // 2097152 bf16
  float* e2w  = ws + 1097728;            // 3145728 f32
  short* ogw  = (short*)(ws + 4243456);  // 3145728 bf16
  float* Sw   = ws + 5816320;            // 3145728 f32
  float* outp = (float*)d_out;

  k_prep<<<321, 256, 0, stream>>>(nf, wl_w, wl_b, wr_w, wr_b, dg_w,
                                  eg_w, ep_w, og_w, lo_w, dp_w,
                                  nlBw, Atw, wTw, dpTw);
  k_gp  <<<7680, 256, 0, stream>>>(eidx, pos, nlBw, Atw, dpTw, dg_b, dp_b, Sw,
                                   efin, ln_w, ln_b, wTw, eg_b, ep_b, og_b, e2w, ogw);
  k_out4<<<1536, 256, 0, stream>>>(Sw, e2w, lno_w, lno_b, wTw + 49152, lo_b, ogw, outp);
}

// Round 17
// 96.613 us; speedup vs baseline: 1.0820x; 1.0820x over previous
//
#include <hip/hip_runtime.h>
#include <math.h>

#define N_NODES 1024
#define DEG     24
#define K_NN    12
#define C_S     384
#define C_Z     128
#define C_G     16
#define N_RBF   64
#define N_EDGES (N_NODES*DEG)

typedef short short8 __attribute__((ext_vector_type(8)));
typedef float f32x4  __attribute__((ext_vector_type(4)));

__device__ __forceinline__ float sigf(float x) {
  return __builtin_amdgcn_rcpf(1.f + __expf(-x));
}

// float -> bf16 (RNE)
__device__ __forceinline__ short f2b(float x) {
  union { float f; unsigned u; } v; v.f = x;
  unsigned r = v.u + 0x7FFFu + ((v.u >> 16) & 1u);
  return (short)(r >> 16);
}
__device__ __forceinline__ float b2f(short s) {
  union { unsigned u; float f; } v; v.u = ((unsigned)(unsigned short)s) << 16;
  return v.f;
}

// ---------------- K1: all input-only prep (R12 form, measured ~10us) ----------------
__global__ __launch_bounds__(256) void k_prep(
    const float* __restrict__ nf, const float* __restrict__ wl_w, const float* __restrict__ wl_b,
    const float* __restrict__ wr_w, const float* __restrict__ wr_b,
    const float* __restrict__ dg_w,
    const float* __restrict__ eg, const float* __restrict__ ep,
    const float* __restrict__ og, const float* __restrict__ lo,
    const float* __restrict__ dp_w,
    short* __restrict__ nlB, short* __restrict__ At,
    short* __restrict__ wT, short* __restrict__ dpT)
{
  __shared__ float rows[4][C_S];
  __shared__ float nrv[4][C_G];
  __shared__ float tb[32][33];
  int b = blockIdx.x, t = threadIdx.x;
  if (b < 256) {
    for (int v = t; v < 4*C_S; v += 256) rows[v/C_S][v%C_S] = nf[(size_t)b*4*C_S + v];
    __syncthreads();
    {
      int nd = t >> 6, lt = t & 63;
      int c = lt >> 1, jseg = lt & 1, cc = c & 15;
      const float* w = (c < 16) ? wl_w : wr_w;
      float acc = 0.f;
      #pragma unroll 8
      for (int j = jseg*192; j < jseg*192 + 192; ++j) acc += rows[nd][j] * w[j*C_G + cc];
      acc += __shfl_xor(acc, 1);
      if (jseg == 0) {
        float v = acc + ((c < 16) ? wl_b[cc] : wr_b[cc]);
        if (c < 16) nlB[(b*4 + nd)*C_G + cc] = f2b(v);
        else nrv[nd][cc] = v;
      }
    }
    __syncthreads();
    {
      int c2 = t & 127, ih = t >> 7;
      float a4[4][8];
      #pragma unroll
      for (int nd = 0; nd < 4; ++nd)
        #pragma unroll
        for (int q = 0; q < 8; ++q) a4[nd][q] = 0.f;
      for (int j = 0; j < C_G; ++j) {
        float w8[8];
        #pragma unroll
        for (int q = 0; q < 8; ++q) w8[q] = dg_w[(size_t)((ih*8 + q)*C_G + j)*C_Z + c2];
        #pragma unroll
        for (int nd = 0; nd < 4; ++nd) {
          float nv = nrv[nd][j];
          #pragma unroll
          for (int q = 0; q < 8; ++q) a4[nd][q] += nv * w8[q];
        }
      }
      #pragma unroll
      for (int nd = 0; nd < 4; ++nd) {
        short8 o8;
        #pragma unroll
        for (int q = 0; q < 8; ++q) o8[q] = f2b(a4[nd][q]);
        *(short8*)&At[(size_t)(b*4 + nd)*2048 + c2*16 + ih*8] = o8;
      }
    }
    return;
  }
  if (b < 320) {
    int bb = b - 256;
    int w = bb >> 4, tile = bb & 15, bi = tile >> 2, bj = tile & 3;
    const float* src = (w == 0) ? eg : (w == 1) ? ep : (w == 2) ? og : lo;
    short* dst = wT + w * 16384;
    int c = t & 31, r0 = t >> 5;
    #pragma unroll
    for (int p = 0; p < 4; ++p) { int r = r0 + p*8; tb[r][c] = src[(bi*32 + r)*128 + bj*32 + c]; }
    __syncthreads();
    #pragma unroll
    for (int p = 0; p < 4; ++p) { int r = r0 + p*8; dst[(bj*32 + r)*128 + bi*32 + c] = f2b(tb[c][r]); }
    return;
  }
  {
    int c2 = t & 127, rh = t >> 7;
    for (int r = rh*36; r < rh*36 + 36; ++r)
      dpT[c2*72 + r] = (r < 64) ? f2b(dp_w[r*128 + c2]) : (short)0;
  }
}

// ---------------- K2: LN + gate GEMVs, 16 edges per block, one barrier (measured ~13us) ----------------
__global__ __launch_bounds__(256) void k_gates2(
    const float* __restrict__ efin, const float* __restrict__ ln_w, const float* __restrict__ ln_b,
    const short* __restrict__ wT,
    const float* __restrict__ eg_b, const float* __restrict__ ep_b, const float* __restrict__ og_b,
    float* __restrict__ e2, short* __restrict__ ogs)
{
  __shared__ short xn[16*136];
  int t = threadIdx.x;
  int ebase = blockIdx.x * 16;
  {
    int el = t >> 4, sub = t & 15, c0 = sub*8;
    float x[8];
    size_t ein = (size_t)(ebase + el) * C_Z + c0;
    float4 v0 = *(const float4*)(efin + ein);
    float4 v1 = *(const float4*)(efin + ein + 4);
    x[0]=v0.x; x[1]=v0.y; x[2]=v0.z; x[3]=v0.w;
    x[4]=v1.x; x[5]=v1.y; x[6]=v1.z; x[7]=v1.w;
    float s = 0.f;
    #pragma unroll
    for (int q = 0; q < 8; ++q) s += x[q];
    s += __shfl_xor(s,1); s += __shfl_xor(s,2); s += __shfl_xor(s,4); s += __shfl_xor(s,8);
    float mean = s * (1.f/128.f);
    float vs = 0.f;
    #pragma unroll
    for (int q = 0; q < 8; ++q) { float d = x[q]-mean; vs += d*d; }
    vs += __shfl_xor(vs,1); vs += __shfl_xor(vs,2); vs += __shfl_xor(vs,4); vs += __shfl_xor(vs,8);
    float rstd = rsqrtf(vs*(1.f/128.f) + 1e-5f);
    short8 o;
    #pragma unroll
    for (int q = 0; q < 8; ++q)
      o[q] = f2b((x[q]-mean)*rstd*ln_w[c0+q] + ln_b[c0+q]);
    *(short8*)&xn[el*136 + c0] = o;
  }
  __syncthreads();
  int wv = t >> 6, lane = t & 63, col = lane & 15, grp = lane >> 4;
  short8 a[4];
  #pragma unroll
  for (int ks = 0; ks < 4; ++ks)
    a[ks] = *(const short8*)&xn[col*136 + ks*32 + grp*8];
  #pragma unroll
  for (int hh = 0; hh < 2; ++hh) {
    int ch = col + 16*(wv*2 + hh);
    f32x4 aE = (f32x4){0.f,0.f,0.f,0.f}, aP = aE, aO = aE;
    #pragma unroll
    for (int ks = 0; ks < 4; ++ks) {
      aE = __builtin_amdgcn_mfma_f32_16x16x32_bf16(
          a[ks], *(const short8*)(wT + (size_t)ch*128 + ks*32 + grp*8), aE, 0, 0, 0);
      aP = __builtin_amdgcn_mfma_f32_16x16x32_bf16(
          a[ks], *(const short8*)(wT + 16384 + (size_t)ch*128 + ks*32 + grp*8), aP, 0, 0, 0);
      aO = __builtin_amdgcn_mfma_f32_16x16x32_bf16(
          a[ks], *(const short8*)(wT + 32768 + (size_t)ch*128 + ks*32 + grp*8), aO, 0, 0, 0);
    }
    float egb = eg_b[ch], epb = ep_b[ch], ogb = og_b[ch];
    #pragma unroll
    for (int r = 0; r < 4; ++r) {
      size_t e = (size_t)(ebase + grp*4 + r);
      e2[e*C_Z + ch]  = sigf(aE[r] + egb) * (aP[r] + epb);
      ogs[e*C_Z + ch] = f2b(sigf(aO[r] + ogb));
    }
  }
}

// ---------------- K3: pairs, one o per wave — R9 VERBATIM core (measured 42.6us) ----------------
// Zero-init accumulators + bias in epilogue: R14's bias-as-C-in variant cost +7us
// (splat movs + register pressure 40->56). No barriers after staging; dpT from global
// (18KB, L1/L2-resident; R12's LDS staging caused 1.77M bank conflicts).
__global__ __launch_bounds__(256) void k_pairs2(
    const int* __restrict__ eidx, const float* __restrict__ pos,
    const short* __restrict__ nlB, const short* __restrict__ At, const short* __restrict__ dpTg,
    const float* __restrict__ dg_b, const float* __restrict__ dp_b,
    const float* __restrict__ e2, const float* __restrict__ lno_w, const float* __restrict__ lno_b,
    short* __restrict__ Un)
{
  __shared__ float p4[DEG][4];
  __shared__ int   s24[DEG];
  __shared__ short nlb[DEG*C_G];
  int t = threadIdx.x;
  int g = blockIdx.x / 6, sub = blockIdx.x - g*6;
  if (t < DEG) {
    int s = eidx[g*DEG + t];
    s24[t] = s;
    p4[t][0] = pos[s*3+0]; p4[t][1] = pos[s*3+1]; p4[t][2] = pos[s*3+2]; p4[t][3] = 0.f;
  }
  __syncthreads();
  for (int v = t; v < DEG*C_G; v += 256)
    nlb[v] = nlB[s24[v>>4]*C_G + (v & 15)];
  __syncthreads();

  int wv = t >> 6, lane = t & 63, col = lane & 15, grp = lane >> 4;
  int o = sub*4 + wv;
  size_t e = (size_t)g*DEG + o;

  float dgb[8], dpb[8];
  #pragma unroll
  for (int q = 0; q < 8; ++q) { int c = col+16*q; dgb[q] = dg_b[c]; dpb[q] = dp_b[c]; }
  const float RS = 3.2f, MUS = 20.f/63.f;

  int n2 = s24[o];
  int o2 = o - 1 - col; if (o2 < 0) o2 += DEG;
  bool vk = (col < K_NN);
  float d;
  {
    float dx = p4[o2][0]-p4[o][0]+1e-8f;
    float dy = p4[o2][1]-p4[o][1]+1e-8f;
    float dz = p4[o2][2]-p4[o][2]+1e-8f;
    d = vk ? sqrtf(dx*dx+dy*dy+dz*dz) : 1.0e6f;
  }
  short8 zz = {0,0,0,0,0,0,0,0};
  short8 a_nl = zz;
  if (vk && grp < 2) a_nl = *(const short8*)&nlb[o2*C_G + grp*8];
  short8 a_r0, a_r1;
  #pragma unroll
  for (int j = 0; j < 8; ++j) {
    float z0 = (d - (float)(grp*8 + j)*MUS)*RS;
    float z1 = (d - (float)(32 + grp*8 + j)*MUS)*RS;
    a_r0[j] = f2b(__expf(-z0*z0));
    a_r1[j] = f2b(__expf(-z1*z1));
  }
  const short8* Ab = (const short8*)(At + (size_t)n2*2048);
  float v1 = 0.f, v2 = 0.f;
  #pragma unroll
  for (int cb = 0; cb < 8; ++cb) {
    f32x4 accg = (f32x4){0.f,0.f,0.f,0.f};
    f32x4 accd = (f32x4){0.f,0.f,0.f,0.f};
    short8 b = (grp < 2) ? Ab[(col+16*cb)*2 + grp] : zz;
    accg = __builtin_amdgcn_mfma_f32_16x16x32_bf16(a_nl, b, accg, 0, 0, 0);
    const short* dbase = dpTg + (col+16*cb)*72 + grp*8;
    accd = __builtin_amdgcn_mfma_f32_16x16x32_bf16(a_r0, *(const short8*)dbase,      accd, 0, 0, 0);
    accd = __builtin_amdgcn_mfma_f32_16x16x32_bf16(a_r1, *(const short8*)(dbase+32), accd, 0, 0, 0);
    float sacc = 0.f;
    #pragma unroll
    for (int r = 0; r < 4; ++r)
      sacc += sigf(accg[r] + dgb[cb]) * (accd[r] + dpb[cb]);
    sacc = (grp == 3) ? 0.f : sacc;   // mask k rows 12..15
    sacc += __shfl_xor(sacc, 16); sacc += __shfl_xor(sacc, 32);
    v1 = (cb == grp)     ? sacc : v1;
    v2 = (cb == grp + 4) ? sacc : v2;
  }
  v1 *= e2[e*C_Z + lane];
  v2 *= e2[e*C_Z + 64 + lane];
  // in-wave LayerNorm of U row
  float s = v1 + v2;
  s += __shfl_xor(s,1); s += __shfl_xor(s,2); s += __shfl_xor(s,4);
  s += __shfl_xor(s,8); s += __shfl_xor(s,16); s += __shfl_xor(s,32);
  float mean = s * (1.f/128.f);
  float d1 = v1 - mean, d2 = v2 - mean;
  float vsum = d1*d1 + d2*d2;
  vsum += __shfl_xor(vsum,1); vsum += __shfl_xor(vsum,2); vsum += __shfl_xor(vsum,4);
  vsum += __shfl_xor(vsum,8); vsum += __shfl_xor(vsum,16); vsum += __shfl_xor(vsum,32);
  float rstd = rsqrtf(vsum*(1.f/128.f) + 1e-5f);
  Un[e*C_Z + lane]      = f2b(d1*rstd*lno_w[lane]      + lno_b[lane]);
  Un[e*C_Z + 64 + lane] = f2b(d2*rstd*lno_w[64 + lane] + lno_b[64 + lane]);
}

// ---------------- K4: out = (Un @ lo_w + lo_b) * ogs; barrier-free (measured ~6us) ----------------
__global__ __launch_bounds__(256) void k_out3(
    const short* __restrict__ Un, const short* __restrict__ wTlo, const float* __restrict__ lo_b,
    const short* __restrict__ ogs, float* __restrict__ out)
{
  int t = threadIdx.x, wv = t >> 6, lane = t & 63, col = lane & 15, grp = lane >> 4;
  int ebase = blockIdx.x * 16;
  short8 ua[4];
  #pragma unroll
  for (int ks = 0; ks < 4; ++ks)
    ua[ks] = *(const short8*)(Un + (size_t)(ebase + col)*C_Z + ks*32 + grp*8);
  #pragma unroll
  for (int hh = 0; hh < 2; ++hh) {
    int ch = col + 16*(wv*2 + hh);
    f32x4 oacc = (f32x4){0.f,0.f,0.f,0.f};
    #pragma unroll
    for (int ks = 0; ks < 4; ++ks)
      oacc = __builtin_amdgcn_mfma_f32_16x16x32_bf16(
          ua[ks], *(const short8*)(wTlo + (size_t)ch*128 + ks*32 + grp*8), oacc, 0, 0, 0);
    float lob = lo_b[ch];
    #pragma unroll
    for (int r = 0; r < 4; ++r) {
      size_t e = (size_t)(ebase + grp*4 + r);
      out[e*C_Z + ch] = (oacc[r] + lob) * b2f(ogs[e*C_Z + ch]);
    }
  }
}

extern "C" void kernel_launch(void* const* d_in, const int* in_sizes, int n_in,
                              void* d_out, int out_size, void* d_ws, size_t ws_size,
                              hipStream_t stream)
{
  const float* nf    = (const float*)d_in[0];
  const float* pos   = (const float*)d_in[1];
  const float* efin  = (const float*)d_in[2];
  const float* ln_w  = (const float*)d_in[3];
  const float* ln_b  = (const float*)d_in[4];
  const float* wl_w  = (const float*)d_in[5];
  const float* wl_b  = (const float*)d_in[6];
  const float* wr_w  = (const float*)d_in[7];
  const float* wr_b  = (const float*)d_in[8];
  const float* ep_w  = (const float*)d_in[9];
  const float* ep_b  = (const float*)d_in[10];
  const float* eg_w  = (const float*)d_in[11];
  const float* eg_b  = (const float*)d_in[12];
  const float* dg_w  = (const float*)d_in[13];
  const float* dg_b  = (const float*)d_in[14];
  const float* dp_w  = (const float*)d_in[15];
  const float* dp_b  = (const float*)d_in[16];
  const float* lno_w = (const float*)d_in[17];
  const float* lno_b = (const float*)d_in[18];
  const float* lo_w  = (const float*)d_in[19];
  const float* lo_b  = (const float*)d_in[20];
  const float* og_w  = (const float*)d_in[21];
  const float* og_b  = (const float*)d_in[22];
  const int*   eidx  = (const int*)d_in[23];
  // d_in[24] = edge_edge_index: structure derived analytically, not read.

  float* ws   = (float*)d_ws;
  short* nlBw = (short*)(ws + 0);        //  16384 bf16
  short* dpTw = (short*)(ws + 8192);     //   9216 bf16
  short* wTw  = (short*)(ws + 16384);    //  65536 bf16 (eg,ep,og,lo)
  short* Atw  = (short*)(ws + 49152);    // 2097152 bf16
  float* e2w  = ws + 1097728;            // 3145728 f32
  short* ogw  = (short*)(ws + 4243456);  // 3145728 bf16
  short* Unw  = (short*)(ws + 5816320);  // 3145728 bf16
  float* outp = (float*)d_out;

  k_prep  <<<321, 256, 0, stream>>>(nf, wl_w, wl_b, wr_w, wr_b, dg_w,
                                    eg_w, ep_w, og_w, lo_w, dp_w,
                                    nlBw, Atw, wTw, dpTw);
  k_gates2<<<1536, 256, 0, stream>>>(efin, ln_w, ln_b, wTw, eg_b, ep_b, og_b, e2w, ogw);
  k_pairs2<<<6144, 256, 0, stream>>>(eidx, pos, nlBw, Atw, dpTw, dg_b, dp_b,
                                     e2w, lno_w, lno_b, Unw);
  k_out3  <<<1536, 256, 0, stream>>>(Unw, wTw + 49152, lo_b, ogw, outp);
}

// Round 19
// 96.270 us; speedup vs baseline: 1.0859x; 1.0036x over previous
//
#include <hip/hip_runtime.h>
#include <math.h>

#define N_NODES 1024
#define DEG     24
#define K_NN    12
#define C_S     384
#define C_Z     128
#define C_G     16
#define N_RBF   64
#define N_EDGES (N_NODES*DEG)

typedef short short8 __attribute__((ext_vector_type(8)));
typedef float f32x4  __attribute__((ext_vector_type(4)));

__device__ __forceinline__ float sigf(float x) {
  return __builtin_amdgcn_rcpf(1.f + __expf(-x));
}

// float -> bf16 (RNE, manual). R18's v_cvt_pk_bf16_f32 inline asm produced wrong
// values (absmax 202 — packing semantics differ from assumption). Keep the twiddle.
__device__ __forceinline__ short f2b(float x) {
  union { float f; unsigned u; } v; v.f = x;
  unsigned r = v.u + 0x7FFFu + ((v.u >> 16) & 1u);
  return (short)(r >> 16);
}
__device__ __forceinline__ float b2f(short s) {
  union { unsigned u; float f; } v; v.u = ((unsigned)(unsigned short)s) << 16;
  return v.f;
}

// ---------------- K1: all input-only prep (R12 form, measured ~10us) ----------------
__global__ __launch_bounds__(256) void k_prep(
    const float* __restrict__ nf, const float* __restrict__ wl_w, const float* __restrict__ wl_b,
    const float* __restrict__ wr_w, const float* __restrict__ wr_b,
    const float* __restrict__ dg_w,
    const float* __restrict__ eg, const float* __restrict__ ep,
    const float* __restrict__ og, const float* __restrict__ lo,
    const float* __restrict__ dp_w,
    short* __restrict__ nlB, short* __restrict__ At,
    short* __restrict__ wT, short* __restrict__ dpT)
{
  __shared__ float rows[4][C_S];
  __shared__ float nrv[4][C_G];
  __shared__ float tb[32][33];
  int b = blockIdx.x, t = threadIdx.x;
  if (b < 256) {
    for (int v = t; v < 4*C_S; v += 256) rows[v/C_S][v%C_S] = nf[(size_t)b*4*C_S + v];
    __syncthreads();
    {
      int nd = t >> 6, lt = t & 63;
      int c = lt >> 1, jseg = lt & 1, cc = c & 15;
      const float* w = (c < 16) ? wl_w : wr_w;
      float acc = 0.f;
      #pragma unroll 8
      for (int j = jseg*192; j < jseg*192 + 192; ++j) acc += rows[nd][j] * w[j*C_G + cc];
      acc += __shfl_xor(acc, 1);
      if (jseg == 0) {
        float v = acc + ((c < 16) ? wl_b[cc] : wr_b[cc]);
        if (c < 16) nlB[(b*4 + nd)*C_G + cc] = f2b(v);
        else nrv[nd][cc] = v;
      }
    }
    __syncthreads();
    {
      int c2 = t & 127, ih = t >> 7;
      float a4[4][8];
      #pragma unroll
      for (int nd = 0; nd < 4; ++nd)
        #pragma unroll
        for (int q = 0; q < 8; ++q) a4[nd][q] = 0.f;
      for (int j = 0; j < C_G; ++j) {
        float w8[8];
        #pragma unroll
        for (int q = 0; q < 8; ++q) w8[q] = dg_w[(size_t)((ih*8 + q)*C_G + j)*C_Z + c2];
        #pragma unroll
        for (int nd = 0; nd < 4; ++nd) {
          float nv = nrv[nd][j];
          #pragma unroll
          for (int q = 0; q < 8; ++q) a4[nd][q] += nv * w8[q];
        }
      }
      #pragma unroll
      for (int nd = 0; nd < 4; ++nd) {
        short8 o8;
        #pragma unroll
        for (int q = 0; q < 8; ++q) o8[q] = f2b(a4[nd][q]);
        *(short8*)&At[(size_t)(b*4 + nd)*2048 + c2*16 + ih*8] = o8;
      }
    }
    return;
  }
  if (b < 320) {
    int bb = b - 256;
    int w = bb >> 4, tile = bb & 15, bi = tile >> 2, bj = tile & 3;
    const float* src = (w == 0) ? eg : (w == 1) ? ep : (w == 2) ? og : lo;
    short* dst = wT + w * 16384;
    int c = t & 31, r0 = t >> 5;
    #pragma unroll
    for (int p = 0; p < 4; ++p) { int r = r0 + p*8; tb[r][c] = src[(bi*32 + r)*128 + bj*32 + c]; }
    __syncthreads();
    #pragma unroll
    for (int p = 0; p < 4; ++p) { int r = r0 + p*8; dst[(bj*32 + r)*128 + bi*32 + c] = f2b(tb[c][r]); }
    return;
  }
  {
    int c2 = t & 127, rh = t >> 7;
    for (int r = rh*36; r < rh*36 + 36; ++r)
      dpT[c2*72 + r] = (r < 64) ? f2b(dp_w[r*128 + c2]) : (short)0;
  }
}

// ---------------- K2: LN + gate GEMVs, 16 edges per block, one barrier (measured ~13us) ----------------
__global__ __launch_bounds__(256) void k_gates2(
    const float* __restrict__ efin, const float* __restrict__ ln_w, const float* __restrict__ ln_b,
    const short* __restrict__ wT,
    const float* __restrict__ eg_b, const float* __restrict__ ep_b, const float* __restrict__ og_b,
    float* __restrict__ e2, short* __restrict__ ogs)
{
  __shared__ short xn[16*136];
  int t = threadIdx.x;
  int ebase = blockIdx.x * 16;
  {
    int el = t >> 4, sub = t & 15, c0 = sub*8;
    float x[8];
    size_t ein = (size_t)(ebase + el) * C_Z + c0;
    float4 v0 = *(const float4*)(efin + ein);
    float4 v1 = *(const float4*)(efin + ein + 4);
    x[0]=v0.x; x[1]=v0.y; x[2]=v0.z; x[3]=v0.w;
    x[4]=v1.x; x[5]=v1.y; x[6]=v1.z; x[7]=v1.w;
    float s = 0.f;
    #pragma unroll
    for (int q = 0; q < 8; ++q) s += x[q];
    s += __shfl_xor(s,1); s += __shfl_xor(s,2); s += __shfl_xor(s,4); s += __shfl_xor(s,8);
    float mean = s * (1.f/128.f);
    float vs = 0.f;
    #pragma unroll
    for (int q = 0; q < 8; ++q) { float d = x[q]-mean; vs += d*d; }
    vs += __shfl_xor(vs,1); vs += __shfl_xor(vs,2); vs += __shfl_xor(vs,4); vs += __shfl_xor(vs,8);
    float rstd = rsqrtf(vs*(1.f/128.f) + 1e-5f);
    short8 o;
    #pragma unroll
    for (int q = 0; q < 8; ++q)
      o[q] = f2b((x[q]-mean)*rstd*ln_w[c0+q] + ln_b[c0+q]);
    *(short8*)&xn[el*136 + c0] = o;
  }
  __syncthreads();
  int wv = t >> 6, lane = t & 63, col = lane & 15, grp = lane >> 4;
  short8 a[4];
  #pragma unroll
  for (int ks = 0; ks < 4; ++ks)
    a[ks] = *(const short8*)&xn[col*136 + ks*32 + grp*8];
  #pragma unroll
  for (int hh = 0; hh < 2; ++hh) {
    int ch = col + 16*(wv*2 + hh);
    f32x4 aE = (f32x4){0.f,0.f,0.f,0.f}, aP = aE, aO = aE;
    #pragma unroll
    for (int ks = 0; ks < 4; ++ks) {
      aE = __builtin_amdgcn_mfma_f32_16x16x32_bf16(
          a[ks], *(const short8*)(wT + (size_t)ch*128 + ks*32 + grp*8), aE, 0, 0, 0);
      aP = __builtin_amdgcn_mfma_f32_16x16x32_bf16(
          a[ks], *(const short8*)(wT + 16384 + (size_t)ch*128 + ks*32 + grp*8), aP, 0, 0, 0);
      aO = __builtin_amdgcn_mfma_f32_16x16x32_bf16(
          a[ks], *(const short8*)(wT + 32768 + (size_t)ch*128 + ks*32 + grp*8), aO, 0, 0, 0);
    }
    float egb = eg_b[ch], epb = ep_b[ch], ogb = og_b[ch];
    #pragma unroll
    for (int r = 0; r < 4; ++r) {
      size_t e = (size_t)(ebase + grp*4 + r);
      e2[e*C_Z + ch]  = sigf(aE[r] + egb) * (aP[r] + epb);
      ogs[e*C_Z + ch] = f2b(sigf(aO[r] + ogb));
    }
  }
}

// ---------------- K3: pairs, one o per wave — R9 VERBATIM core (measured 42.6us) + fmaf RBF fold ----------------
// Zero-init accumulators + bias in epilogue. dpT from global (L2-resident).
__global__ __launch_bounds__(256) void k_pairs2(
    const int* __restrict__ eidx, const float* __restrict__ pos,
    const short* __restrict__ nlB, const short* __restrict__ At, const short* __restrict__ dpTg,
    const float* __restrict__ dg_b, const float* __restrict__ dp_b,
    const float* __restrict__ e2, const float* __restrict__ lno_w, const float* __restrict__ lno_b,
    short* __restrict__ Un)
{
  __shared__ float p4[DEG][4];
  __shared__ int   s24[DEG];
  __shared__ short nlb[DEG*C_G];
  int t = threadIdx.x;
  int g = blockIdx.x / 6, sub = blockIdx.x - g*6;
  if (t < DEG) {
    int s = eidx[g*DEG + t];
    s24[t] = s;
    p4[t][0] = pos[s*3+0]; p4[t][1] = pos[s*3+1]; p4[t][2] = pos[s*3+2]; p4[t][3] = 0.f;
  }
  __syncthreads();
  for (int v = t; v < DEG*C_G; v += 256)
    nlb[v] = nlB[s24[v>>4]*C_G + (v & 15)];
  __syncthreads();

  int wv = t >> 6, lane = t & 63, col = lane & 15, grp = lane >> 4;
  int o = sub*4 + wv;
  size_t e = (size_t)g*DEG + o;

  float dgb[8], dpb[8];
  #pragma unroll
  for (int q = 0; q < 8; ++q) { int c = col+16*q; dgb[q] = dg_b[c]; dpb[q] = dp_b[c]; }
  const float RS = 3.2f, MUSRS = (20.f/63.f)*3.2f;

  int n2 = s24[o];
  int o2 = o - 1 - col; if (o2 < 0) o2 += DEG;
  bool vk = (col < K_NN);
  float d;
  {
    float dx = p4[o2][0]-p4[o][0]+1e-8f;
    float dy = p4[o2][1]-p4[o][1]+1e-8f;
    float dz = p4[o2][2]-p4[o][2]+1e-8f;
    d = vk ? sqrtf(dx*dx+dy*dy+dz*dz) : 1.0e6f;
  }
  short8 zz = {0,0,0,0,0,0,0,0};
  short8 a_nl = zz;
  if (vk && grp < 2) a_nl = *(const short8*)&nlb[o2*C_G + grp*8];
  short8 a_r0, a_r1;
  #pragma unroll
  for (int j = 0; j < 8; ++j) {
    float z0 = fmaf(d, RS, -(float)(grp*8 + j)*MUSRS);
    float z1 = fmaf(d, RS, -(float)(32 + grp*8 + j)*MUSRS);
    a_r0[j] = f2b(__expf(-z0*z0));
    a_r1[j] = f2b(__expf(-z1*z1));
  }
  const short8* Ab = (const short8*)(At + (size_t)n2*2048);
  float v1 = 0.f, v2 = 0.f;
  #pragma unroll
  for (int cb = 0; cb < 8; ++cb) {
    f32x4 accg = (f32x4){0.f,0.f,0.f,0.f};
    f32x4 accd = (f32x4){0.f,0.f,0.f,0.f};
    short8 b = (grp < 2) ? Ab[(col+16*cb)*2 + grp] : zz;
    accg = __builtin_amdgcn_mfma_f32_16x16x32_bf16(a_nl, b, accg, 0, 0, 0);
    const short* dbase = dpTg + (col+16*cb)*72 + grp*8;
    accd = __builtin_amdgcn_mfma_f32_16x16x32_bf16(a_r0, *(const short8*)dbase,      accd, 0, 0, 0);
    accd = __builtin_amdgcn_mfma_f32_16x16x32_bf16(a_r1, *(const short8*)(dbase+32), accd, 0, 0, 0);
    float sacc = 0.f;
    #pragma unroll
    for (int r = 0; r < 4; ++r)
      sacc += sigf(accg[r] + dgb[cb]) * (accd[r] + dpb[cb]);
    sacc = (grp == 3) ? 0.f : sacc;   // mask k rows 12..15
    sacc += __shfl_xor(sacc, 16); sacc += __shfl_xor(sacc, 32);
    v1 = (cb == grp)     ? sacc : v1;
    v2 = (cb == grp + 4) ? sacc : v2;
  }
  v1 *= e2[e*C_Z + lane];
  v2 *= e2[e*C_Z + 64 + lane];
  // in-wave LayerNorm of U row
  float s = v1 + v2;
  s += __shfl_xor(s,1); s += __shfl_xor(s,2); s += __shfl_xor(s,4);
  s += __shfl_xor(s,8); s += __shfl_xor(s,16); s += __shfl_xor(s,32);
  float mean = s * (1.f/128.f);
  float d1 = v1 - mean, d2 = v2 - mean;
  float vsum = d1*d1 + d2*d2;
  vsum += __shfl_xor(vsum,1); vsum += __shfl_xor(vsum,2); vsum += __shfl_xor(vsum,4);
  vsum += __shfl_xor(vsum,8); vsum += __shfl_xor(vsum,16); vsum += __shfl_xor(vsum,32);
  float rstd = rsqrtf(vsum*(1.f/128.f) + 1e-5f);
  Un[e*C_Z + lane]      = f2b(d1*rstd*lno_w[lane]      + lno_b[lane]);
  Un[e*C_Z + 64 + lane] = f2b(d2*rstd*lno_w[64 + lane] + lno_b[64 + lane]);
}

// ---------------- K4: out = (Un @ lo_w + lo_b) * ogs; barrier-free (measured ~6us) ----------------
__global__ __launch_bounds__(256) void k_out3(
    const short* __restrict__ Un, const short* __restrict__ wTlo, const float* __restrict__ lo_b,
    const short* __restrict__ ogs, float* __restrict__ out)
{
  int t = threadIdx.x, wv = t >> 6, lane = t & 63, col = lane & 15, grp = lane >> 4;
  int ebase = blockIdx.x * 16;
  short8 ua[4];
  #pragma unroll
  for (int ks = 0; ks < 4; ++ks)
    ua[ks] = *(const short8*)(Un + (size_t)(ebase + col)*C_Z + ks*32 + grp*8);
  #pragma unroll
  for (int hh = 0; hh < 2; ++hh) {
    int ch = col + 16*(wv*2 + hh);
    f32x4 oacc = (f32x4){0.f,0.f,0.f,0.f};
    #pragma unroll
    for (int ks = 0; ks < 4; ++ks)
      oacc = __builtin_amdgcn_mfma_f32_16x16x32_bf16(
          ua[ks], *(const short8*)(wTlo + (size_t)ch*128 + ks*32 + grp*8), oacc, 0, 0, 0);
    float lob = lo_b[ch];
    #pragma unroll
    for (int r = 0; r < 4; ++r) {
      size_t e = (size_t)(ebase + grp*4 + r);
      out[e*C_Z + ch] = (oacc[r] + lob) * b2f(ogs[e*C_Z + ch]);
    }
  }
}

extern "C" void kernel_launch(void* const* d_in, const int* in_sizes, int n_in,
                              void* d_out, int out_size, void* d_ws, size_t ws_size,
                              hipStream_t stream)
{
  const float* nf    = (const float*)d_in[0];
  const float* pos   = (const float*)d_in[1];
  const float* efin  = (const float*)d_in[2];
  const float* ln_w  = (const float*)d_in[3];
  const float* ln_b  = (const float*)d_in[4];
  const float* wl_w  = (const float*)d_in[5];
  const float* wl_b  = (const float*)d_in[6];
  const float* wr_w  = (const float*)d_in[7];
  const float* wr_b  = (const float*)d_in[8];
  const float* ep_w  = (const float*)d_in[9];
  const float* ep_b  = (const float*)d_in[10];
  const float* eg_w  = (const float*)d_in[11];
  const float* eg_b  = (const float*)d_in[12];
  const float* dg_w  = (const float*)d_in[13];
  const float* dg_b  = (const float*)d_in[14];
  const float* dp_w  = (const float*)d_in[15];
  const float* dp_b  = (const float*)d_in[16];
  const float* lno_w = (const float*)d_in[17];
  const float* lno_b = (const float*)d_in[18];
  const float* lo_w  = (const float*)d_in[19];
  const float* lo_b  = (const float*)d_in[20];
  const float* og_w  = (const float*)d_in[21];
  const float* og_b  = (const float*)d_in[22];
  const int*   eidx  = (const int*)d_in[23];
  // d_in[24] = edge_edge_index: structure derived analytically, not read.

  float* ws   = (float*)d_ws;
  short* nlBw = (short*)(ws + 0);        //  16384 bf16
  short* dpTw = (short*)(ws + 8192);     //   9216 bf16
  short* wTw  = (short*)(ws + 16384);    //  65536 bf16 (eg,ep,og,lo)
  short* Atw  = (short*)(ws + 49152);    // 2097152 bf16
  float* e2w  = ws + 1097728;            // 3145728 f32
  short* ogw  = (short*)(ws + 4243456);  // 3145728 bf16
  short* Unw  = (short*)(ws + 5816320);  // 3145728 bf16
  float* outp = (float*)d_out;

  k_prep  <<<321, 256, 0, stream>>>(nf, wl_w, wl_b, wr_w, wr_b, dg_w,
                                    eg_w, ep_w, og_w, lo_w, dp_w,
                                    nlBw, Atw, wTw, dpTw);
  k_gates2<<<1536, 256, 0, stream>>>(efin, ln_w, ln_b, wTw, eg_b, ep_b, og_b, e2w, ogw);
  k_pairs2<<<6144, 256, 0, stream>>>(eidx, pos, nlBw, Atw, dpTw, dg_b, dp_b,
                                     e2w, lno_w, lno_b, Unw);
  k_out3  <<<1536, 256, 0, stream>>>(Unw, wTw + 49152, lo_b, ogw, outp);
}